// Round 8
// baseline (35.252 us; speedup 1.0000x reference)
//
#include <hip/hip_runtime.h>
#include <hip/hip_fp16.h>

#define NPTS 8192
#define KNN  15
#define QPW  2                // queries per wave
#define WPB  8                // waves per block
#define TPB  (WPB * 64)       // 512 threads
#define SEG  64               // candidate buffer capacity per query

__device__ __forceinline__ int prefix_below(unsigned long long m) {
  return (int)__builtin_amdgcn_mbcnt_hi((unsigned int)(m >> 32),
            __builtin_amdgcn_mbcnt_lo((unsigned int)m, 0u));
}

// Packed fp16 min (ROCm header lacks __hmin2): single v_pk_min_f16.
__device__ __forceinline__ __half2 hmin2(__half2 a, __half2 b) {
  __half2 r;
  asm("v_pk_min_f16 %0, %1, %2" : "=v"(r) : "v"(a), "v"(b));
  return r;
}

// Ascending bitonic sort of one u32 per lane across a 64-lane wave.
__device__ __forceinline__ unsigned int bitonic_sort_u32(unsigned int v, int lane) {
#pragma unroll
  for (int k = 2; k <= 64; k <<= 1) {
#pragma unroll
    for (int j = k >> 1; j > 0; j >>= 1) {
      unsigned int o = __shfl_xor(v, j, 64);
      bool keep_min = ((lane & k) == 0) == ((lane & j) == 0);
      unsigned int lo = (v < o) ? v : o;
      unsigned int hi = (v < o) ? o : v;
      v = keep_min ? lo : hi;
    }
  }
  return v;
}

// Ascending bitonic sort of one u64 per lane across a 64-lane wave.
__device__ __forceinline__ unsigned long long bitonic_sort_u64(unsigned long long v, int lane) {
#pragma unroll
  for (int k = 2; k <= 64; k <<= 1) {
#pragma unroll
    for (int j = k >> 1; j > 0; j >>= 1) {
      unsigned long long o = __shfl_xor(v, j, 64);
      bool keep_min = ((lane & k) == 0) == ((lane & j) == 0);
      unsigned long long lo = (v < o) ? v : o;
      unsigned long long hi = (v < o) ? o : v;
      v = keep_min ? lo : hi;
    }
  }
  return v;
}

__global__ __launch_bounds__(TPB)
void knn_kernel(const float* __restrict__ x, const int* __restrict__ y,
                float* __restrict__ out) {
  // sp layout: uint4 j = (xpair, ypair, xpair, ypair) covering points 4j..4j+3,
  // each pair is packed half2 of two consecutive points' coords.
  __shared__ __align__(16) unsigned int sp[NPTS];   // 32 KB fp16 screening copy
  __shared__ unsigned int ybits[NPTS / 32];         // 1 KB label bitset
  __shared__ unsigned int buf[WPB][QPW][SEG];       // 4 KB candidate indices

  const int tid = threadIdx.x;

  // ---- stage fp16-packed points and label bitset ----
  const float4* gx4 = (const float4*)x;             // pairs of points
#pragma unroll
  for (int i = tid; i < NPTS / 2; i += TPB) {
    float4 p = gx4[i];
    __half2 hx = __floats2half2_rn(p.x, p.z);
    __half2 hy = __floats2half2_rn(p.y, p.w);
    sp[2 * i]     = *(const unsigned int*)&hx;
    sp[2 * i + 1] = *(const unsigned int*)&hy;
  }
  if (tid < NPTS / 32) {
    const int4* yy = (const int4*)(y + (tid << 5));
    unsigned int b = 0;
#pragma unroll
    for (int k2 = 0; k2 < 8; ++k2) {
      int4 v = yy[k2];
      b |= ((unsigned int)(v.x & 1) << (4 * k2)) |
           ((unsigned int)(v.y & 1) << (4 * k2 + 1)) |
           ((unsigned int)(v.z & 1) << (4 * k2 + 2)) |
           ((unsigned int)(v.w & 1) << (4 * k2 + 3));
    }
    ybits[tid] = b;
  }
  __syncthreads();   // the only barrier; waves are independent below

  const int w = tid >> 6;
  const int lane = tid & 63;
  const int q0 = ((int)blockIdx.x * WPB + w) * QPW;
  const float2 xqa = ((const float2*)x)[q0];        // exact fp32 query coords
  const float2 xqb = ((const float2*)x)[q0 + 1];
  const __half2 qxa = __floats2half2_rn(xqa.x, xqa.x);  // same rounding as staged
  const __half2 qya = __floats2half2_rn(xqa.y, xqa.y);
  const __half2 qxb = __floats2half2_rn(xqb.x, xqb.x);
  const __half2 qyb = __floats2half2_rn(xqb.y, xqb.y);

  const uint4* sp4 = (const uint4*)sp;
  // Phase stagger: co-resident waves start the scan at different positions so
  // DS and VALU demand spread instead of bursting in lockstep. s^off is a
  // bijection on [0,32).
  const int off = ((w << 2) | ((int)blockIdx.x & 3)) & 31;

  // ---- pass 1: per-lane fp16 min per query (self included, d=0) ----
  __half2 mma = __floats2half2_rn(6.0e4f, 6.0e4f);
  __half2 mmb = mma;
#pragma unroll 4
  for (int s = 0; s < 32; ++s) {
    uint4 v = sp4[((s ^ off) << 6) + lane];
    __half2 px0 = *(const __half2*)&v.x, py0 = *(const __half2*)&v.y;
    __half2 px1 = *(const __half2*)&v.z, py1 = *(const __half2*)&v.w;
    __half2 adx0 = __hsub2(px0, qxa), ady0 = __hsub2(py0, qya);
    __half2 adx1 = __hsub2(px1, qxa), ady1 = __hsub2(py1, qya);
    __half2 da0 = __hfma2(adx0, adx0, __hmul2(ady0, ady0));
    __half2 da1 = __hfma2(adx1, adx1, __hmul2(ady1, ady1));
    mma = hmin2(mma, hmin2(da0, da1));
    __half2 bdx0 = __hsub2(px0, qxb), bdy0 = __hsub2(py0, qyb);
    __half2 bdx1 = __hsub2(px1, qxb), bdy1 = __hsub2(py1, qyb);
    __half2 db0 = __hfma2(bdx0, bdx0, __hmul2(bdy0, bdy0));
    __half2 db1 = __hfma2(bdx1, bdx1, __hmul2(bdy1, bdy1));
    mmb = hmin2(mmb, hmin2(db0, db1));
  }

  // 16th-smallest lane-min per query: >=16 distinct points with fp16 d <= T,
  // at most one self => T upper-bounds the fp16 d of the true 16th point.
  // Margin covers fp16<->fp64 discrepancy both ways (coord rounding ~2e-3 abs).
  __half2 Tf2a, Tf2b;
  {
    float m = fminf(__low2float(mma), __high2float(mma));
    unsigned int srt = bitonic_sort_u32(__float_as_uint(m), lane);
    const float T = __uint_as_float(__shfl(srt, KNN, 64));
    const float M = 0.035f * sqrtf(T) + 2.0e-4f + 0.01f * T;
    __half hT = __float2half_rn(T + M);
    hT = __ushort_as_half((unsigned short)(__half_as_ushort(hT) + 2));
    Tf2a = __half2half2(hT);
  }
  {
    float m = fminf(__low2float(mmb), __high2float(mmb));
    unsigned int srt = bitonic_sort_u32(__float_as_uint(m), lane);
    const float T = __uint_as_float(__shfl(srt, KNN, 64));
    const float M = 0.035f * sqrtf(T) + 2.0e-4f + 0.01f * T;
    __half hT = __float2half_rn(T + M);
    hT = __ushort_as_half((unsigned short)(__half_as_ushort(hT) + 2));
    Tf2b = __half2half2(hT);
  }

  // ---- pass 2: collect indices with fp16 d <= Tf (bit-identical d to pass 1) ----
  int cA = 0, cB = 0;
#pragma unroll 2
  for (int s = 0; s < 32; ++s) {
    const int si = s ^ off;
    uint4 v = sp4[(si << 6) + lane];
    __half2 px0 = *(const __half2*)&v.x, py0 = *(const __half2*)&v.y;
    __half2 px1 = *(const __half2*)&v.z, py1 = *(const __half2*)&v.w;
    const int jb = (si << 8) + (lane << 2);        // first of this lane's 4 points

    {  // query A
      __half2 dx0 = __hsub2(px0, qxa), dy0 = __hsub2(py0, qya);
      __half2 dx1 = __hsub2(px1, qxa), dy1 = __hsub2(py1, qya);
      __half2 d0 = __hfma2(dx0, dx0, __hmul2(dy0, dy0));
      __half2 d1 = __hfma2(dx1, dx1, __hmul2(dy1, dy1));
      __half2 t0 = __hsub2(Tf2a, d0);              // sign clear <=> candidate
      __half2 t1 = __hsub2(Tf2a, d1);
      unsigned int s0 = *(const unsigned int*)&t0;
      unsigned int s1 = *(const unsigned int*)&t1;
      if (__any((s0 & s1 & 0x80008000u) != 0x80008000u)) {
        bool c0 = (s0 & 0x00008000u) == 0;
        bool c1 = (s0 & 0x80000000u) == 0;
        bool c2 = (s1 & 0x00008000u) == 0;
        bool c3 = (s1 & 0x80000000u) == 0;
        unsigned long long k0 = __ballot(c0);
        if (c0) { int o = cA + prefix_below(k0); if (o < SEG) buf[w][0][o] = jb; }
        cA += __popcll(k0);
        unsigned long long k1 = __ballot(c1);
        if (c1) { int o = cA + prefix_below(k1); if (o < SEG) buf[w][0][o] = jb + 1; }
        cA += __popcll(k1);
        unsigned long long k2 = __ballot(c2);
        if (c2) { int o = cA + prefix_below(k2); if (o < SEG) buf[w][0][o] = jb + 2; }
        cA += __popcll(k2);
        unsigned long long k3 = __ballot(c3);
        if (c3) { int o = cA + prefix_below(k3); if (o < SEG) buf[w][0][o] = jb + 3; }
        cA += __popcll(k3);
      }
    }
    {  // query B
      __half2 dx0 = __hsub2(px0, qxb), dy0 = __hsub2(py0, qyb);
      __half2 dx1 = __hsub2(px1, qxb), dy1 = __hsub2(py1, qyb);
      __half2 d0 = __hfma2(dx0, dx0, __hmul2(dy0, dy0));
      __half2 d1 = __hfma2(dx1, dx1, __hmul2(dy1, dy1));
      __half2 t0 = __hsub2(Tf2b, d0);
      __half2 t1 = __hsub2(Tf2b, d1);
      unsigned int s0 = *(const unsigned int*)&t0;
      unsigned int s1 = *(const unsigned int*)&t1;
      if (__any((s0 & s1 & 0x80008000u) != 0x80008000u)) {
        bool c0 = (s0 & 0x00008000u) == 0;
        bool c1 = (s0 & 0x80000000u) == 0;
        bool c2 = (s1 & 0x00008000u) == 0;
        bool c3 = (s1 & 0x80000000u) == 0;
        unsigned long long k0 = __ballot(c0);
        if (c0) { int o = cB + prefix_below(k0); if (o < SEG) buf[w][1][o] = jb; }
        cB += __popcll(k0);
        unsigned long long k1 = __ballot(c1);
        if (c1) { int o = cB + prefix_below(k1); if (o < SEG) buf[w][1][o] = jb + 1; }
        cB += __popcll(k1);
        unsigned long long k2 = __ballot(c2);
        if (c2) { int o = cB + prefix_below(k2); if (o < SEG) buf[w][1][o] = jb + 2; }
        cB += __popcll(k2);
        unsigned long long k3 = __ballot(c3);
        if (c3) { int o = cB + prefix_below(k3); if (o < SEG) buf[w][1][o] = jb + 3; }
        cB += __popcll(k3);
      }
    }
  }

  // ---- final: exact fp64 keys from original fp32 coords, sort, vote ----
#pragma unroll
  for (int qi = 0; qi < QPW; ++qi) {
    const int q = q0 + qi;
    const float2 xq = (qi == 0) ? xqa : xqb;
    int C = (qi == 0) ? cA : cB;
    C = (C > SEG) ? SEG : C;                       // expected ~26, >=16 certified
    unsigned long long kv = ~0ull;
    if (lane < C) {
      int jj = (int)buf[w][qi][lane];
      float2 pj = ((const float2*)x)[jj];
      double dx = (double)xq.x - (double)pj.x;     // exact fp32->fp64
      double dy = (double)xq.y - (double)pj.y;
      double dd = dx * dx + dy * dy;               // rel err ~1e-16
      kv = ((unsigned long long)__double_as_longlong(dd) & ~0x1FFFull) |
           (unsigned long long)jj;                 // tie-break: lower index
      if (jj == q) kv = ~0ull;                     // drop self
    }
    kv = bitonic_sort_u64(kv, lane);
    int j15 = (int)(kv & 0x1FFFull);
    int lbl = (int)((ybits[j15 >> 5] >> (j15 & 31)) & 1u);
    unsigned long long vm = __ballot((lane < KNN) && lbl);
    if (lane == 0) out[q] = (__popcll(vm) >= 8) ? 1.0f : 0.0f;   // sum > 7.5
  }
}

extern "C" void kernel_launch(void* const* d_in, const int* in_sizes, int n_in,
                              void* d_out, int out_size, void* d_ws, size_t ws_size,
                              hipStream_t stream) {
  const float* x = (const float*)d_in[0];
  const int* y = (const int*)d_in[1];
  float* out = (float*)d_out;
  dim3 grid(NPTS / (WPB * QPW));   // 512 blocks x 8 waves, 2 queries per wave
  dim3 block(TPB);
  hipLaunchKernelGGL(knn_kernel, grid, block, 0, stream, x, y, out);
}